// Round 4
// baseline (32.271 us; speedup 1.0000x reference)
//
#include <hip/hip_runtime.h>

#define N_NODES 2048
#define WORDS   64          // N_NODES / 32
#define E_MAX_OUT 1048576
#define FDIM    8
#define EL_CAP  64          // per-row original-edge list capacity (Poisson(16): P(>=64) ~ 1e-20)

// ws layout: a_bits(512K) | c_bits(512K) | rel_off(512K) | row_cnt(8K) | ecnt(8K) | elist(512K)

// ---------------- init: zero attr region + a_bits + ecnt ----------------
__global__ void k_init(float* __restrict__ out_attr, unsigned* __restrict__ a_bits,
                       int* __restrict__ ecnt) {
    int tid = blockIdx.x * blockDim.x + threadIdx.x;
    int nth = gridDim.x * blockDim.x;
    const int A4 = FDIM * E_MAX_OUT / 4;           // 2,097,152 float4 = 32 MB
    float4* o4 = (float4*)out_attr;
    for (int p = tid; p < A4; p += nth) o4[p] = make_float4(0.f, 0.f, 0.f, 0.f);
    uint4* a4 = (uint4*)a_bits;
    for (int p = tid; p < N_NODES * WORDS / 4; p += nth) a4[p] = make_uint4(0u, 0u, 0u, 0u);
    for (int p = tid; p < N_NODES; p += nth) ecnt[p] = 0;
}

// ---------------- build adjacency bitset + per-row edge lists ----------------
__global__ void k_build(const int* __restrict__ ei, int E, unsigned* __restrict__ a_bits,
                        int* __restrict__ ecnt, int* __restrict__ elist) {
    int e = blockIdx.x * blockDim.x + threadIdx.x;
    if (e >= E) return;
    int s = ei[e];
    int d = ei[E + e];
    atomicOr(&a_bits[s * WORDS + (d >> 5)], 1u << (d & 31));
    int slot = atomicAdd(&ecnt[s], 1);
    if (slot < EL_CAP) elist[s * EL_CAP + slot] = e;
}

// ---------------- two-hop: one wave per row, 4 rows per block ----------------
__global__ void __launch_bounds__(256) k_twohop(const unsigned* __restrict__ a_bits,
                                                unsigned* __restrict__ c_bits,
                                                int* __restrict__ rel_off,
                                                int* __restrict__ row_cnt) {
    int lane = threadIdx.x & 63;
    int wv   = threadIdx.x >> 6;
    int i    = blockIdx.x * 4 + wv;
    __shared__ int nbr[4][256];
    __shared__ int ncnt_sh[4];

    unsigned r = a_bits[i * WORDS + lane];
    int pc = __popc(r);
    int incl = pc;
    for (int off = 1; off < 64; off <<= 1) {
        int v = __shfl_up(incl, off, 64);
        if (lane >= off) incl += v;
    }
    int base = incl - pc;
    unsigned bits = r;
    int wb = lane << 5;
    while (bits) {
        int b = __ffs(bits) - 1;
        bits &= bits - 1;
        nbr[wv][base++] = wb + b;
    }
    if (lane == 63) ncnt_sh[wv] = incl;
    __syncthreads();

    int nc = ncnt_sh[wv];
    const int* nb = nbr[wv];
    unsigned acc = 0u;
    int j = 0;
    for (; j + 4 <= nc; j += 4) {
        unsigned x0 = a_bits[nb[j]     * WORDS + lane];
        unsigned x1 = a_bits[nb[j + 1] * WORDS + lane];
        unsigned x2 = a_bits[nb[j + 2] * WORDS + lane];
        unsigned x3 = a_bits[nb[j + 3] * WORDS + lane];
        acc |= (x0 | x1) | (x2 | x3);
    }
    for (; j < nc; ++j) acc |= a_bits[nb[j] * WORDS + lane];

    if (lane == (i >> 5)) acc &= ~(1u << (i & 31));  // remove self-loop (two-hop)
    acc |= r;                                         // union original edges
    c_bits[i * WORDS + lane] = acc;

    int cnt = __popc(acc);
    int incl2 = cnt;
    for (int off = 1; off < 64; off <<= 1) {
        int v = __shfl_up(incl2, off, 64);
        if (lane >= off) incl2 += v;
    }
    rel_off[i * WORDS + lane] = incl2 - cnt;
    if (lane == 63) row_cnt[i] = incl2;
}

// ---------------- fused emit + attr + tail padding (no separate scan) ----------------
// Block i (128 thr): in-block masked reduce over row_cnt -> row_off_i and count.
// wave0 emits rows/cols of row i; wave1 scatters attrs of row i's original edges
// (same row_off_i); all threads write block's slice of the -1 tail.
__global__ void __launch_bounds__(128) k_emit_attr(const unsigned* __restrict__ c_bits,
                                                   const int* __restrict__ rel_off,
                                                   const int* __restrict__ row_cnt,
                                                   const int* __restrict__ ei,
                                                   const float* __restrict__ attr, int E,
                                                   const int* __restrict__ ecnt,
                                                   const int* __restrict__ elist,
                                                   float* __restrict__ out) {
    int i    = blockIdx.x;
    int t    = threadIdx.x;
    int lane = t & 63;
    int wave = t >> 6;
    __shared__ int sh_lt[2], sh_all[2];

    // masked reduction: row_off_i = sum(row_cnt[j] for j < i); count = sum(all)
    int p_lt = 0, p_all = 0;
    #pragma unroll
    for (int q = 0; q < N_NODES / 128; ++q) {
        int idx = t * (N_NODES / 128) + q;
        int v = row_cnt[idx];
        p_all += v;
        if (idx < i) p_lt += v;
    }
    for (int off = 32; off; off >>= 1) {
        p_lt  += __shfl_down(p_lt,  off, 64);
        p_all += __shfl_down(p_all, off, 64);
    }
    if (lane == 0) { sh_lt[wave] = p_lt; sh_all[wave] = p_all; }
    __syncthreads();
    int row_off_i = sh_lt[0] + sh_lt[1];
    int count     = sh_all[0] + sh_all[1];

    if (wave == 0) {
        // emit rows/cols of row i
        unsigned c = c_bits[i * WORDS + lane];
        int p = row_off_i + rel_off[i * WORDS + lane];
        float fi = (float)i;
        int wb = lane << 5;
        while (c) {
            int b = __ffs(c) - 1;
            c &= c - 1;
            out[p]             = fi;
            out[E_MAX_OUT + p] = (float)(wb + b);
            ++p;
        }
    } else {
        // scatter attrs of row i's original edges: 4 lanes per edge
        float* oattr = out + 2 * E_MAX_OUT;
        int ne = ecnt[i];
        int q  = lane & 3;
        for (int slot = lane >> 2; slot < ne; slot += 16) {
            int e = elist[i * EL_CAP + slot];
            int d = ei[E + e];
            int dw = d >> 5;
            unsigned cw = c_bits[i * WORDS + dw];
            int p = row_off_i + rel_off[i * WORDS + dw]
                  + __popc(cw & ((1u << (d & 31)) - 1u));
            atomicAdd(&oattr[p * FDIM + 2 * q],     attr[e * FDIM + 2 * q]);
            atomicAdd(&oattr[p * FDIM + 2 * q + 1], attr[e * FDIM + 2 * q + 1]);
        }
    }

    // -1 tail padding for rows/cols: block's slice of [count, E_MAX_OUT)
    long long P = (long long)(E_MAX_OUT - count);
    int s0 = count + (int)(P * i / N_NODES);
    int s1 = count + (int)(P * (i + 1) / N_NODES);
    for (int p = s0 + t; p < s1; p += 128) {
        out[p]             = -1.0f;
        out[E_MAX_OUT + p] = -1.0f;
    }
}

extern "C" void kernel_launch(void* const* d_in, const int* in_sizes, int n_in,
                              void* d_out, int out_size, void* d_ws, size_t ws_size,
                              hipStream_t stream) {
    const int*   ei   = (const int*)d_in[1];     // [2, E]
    const float* attr = (const float*)d_in[2];   // [E, 8]
    int E = in_sizes[1] / 2;

    float* out = (float*)d_out;                  // rows | cols | attrs
    unsigned char* ws = (unsigned char*)d_ws;
    unsigned* a_bits  = (unsigned*)(ws);                          // 512 KB
    unsigned* c_bits  = (unsigned*)(ws + 512 * 1024);             // 512 KB
    int*      rel_off = (int*)(ws + 1024 * 1024);                 // 512 KB
    int*      row_cnt = (int*)(ws + 1536 * 1024);                 // 8 KB
    int*      ecnt    = (int*)(ws + 1544 * 1024);                 // 8 KB
    int*      elist   = (int*)(ws + 1552 * 1024);                 // 512 KB

    k_init     <<<2048, 256, 0, stream>>>(out + 2 * E_MAX_OUT, a_bits, ecnt);
    k_build    <<<(E + 255) / 256, 256, 0, stream>>>(ei, E, a_bits, ecnt, elist);
    k_twohop   <<<N_NODES / 4, 256, 0, stream>>>(a_bits, c_bits, rel_off, row_cnt);
    k_emit_attr<<<N_NODES, 128, 0, stream>>>(c_bits, rel_off, row_cnt, ei, attr, E,
                                             ecnt, elist, out);
}